// Round 7
// baseline (238.110 us; speedup 1.0000x reference)
//
#include <hip/hip_runtime.h>
#include <hip/hip_bf16.h>

// Problem constants (B=4, S=2048, D=512, H=8, Dh=64)
#define BATCH 4
#define SEQ   2048
#define DIM   512
#define NH    8
#define DH    64
#define NTOK  (BATCH*SEQ)        // 8192

typedef __bf16 bf16x8 __attribute__((ext_vector_type(8)));
typedef __bf16 bf16x4 __attribute__((ext_vector_type(4)));
typedef float  f32x4  __attribute__((ext_vector_type(4)));

#define MFMA16(a,b,c) __builtin_amdgcn_mfma_f32_16x16x32_bf16((a),(b),(c),0,0,0)

// async global->LDS, 16B per lane; LDS dest = wave-uniform base + lane*16
__device__ __forceinline__ void async_ld16(const __bf16* g, __bf16* l) {
  __builtin_amdgcn_global_load_lds(
      (const __attribute__((address_space(1))) void*)g,
      (__attribute__((address_space(3))) void*)l, 16, 0, 0);
}

// ---------------------------------------------------------------------------
// fp32 -> bf16 convert: x (524288 chunks) + 4 weights (131072 chunks), 1 launch
// ---------------------------------------------------------------------------
__global__ __launch_bounds__(256) void cvt_all(
    const float* __restrict__ x,
    const float* __restrict__ s0, const float* __restrict__ s1,
    const float* __restrict__ s2, const float* __restrict__ s3,
    __bf16* __restrict__ xb,
    __bf16* __restrict__ o0, __bf16* __restrict__ o1,
    __bf16* __restrict__ o2, __bf16* __restrict__ o3) {
  int i = blockIdx.x * blockDim.x + threadIdx.x;
  const float* src;
  __bf16* dst;
  int off;
  if (i < NTOK*DIM/8) {
    src = x; dst = xb; off = i;
  } else {
    int w = i - NTOK*DIM/8;
    const int which = w >> 15;
    off = w & 32767;
    src = (which == 0) ? s0 : (which == 1) ? s1 : (which == 2) ? s2 : s3;
    dst = (which == 0) ? o0 : (which == 1) ? o1 : (which == 2) ? o2 : o3;
  }
  const float4* s = (const float4*)src;
  float4 a = s[2*off], b = s[2*off+1];
  bf16x8 o;
  o[0] = (__bf16)a.x; o[1] = (__bf16)a.y; o[2] = (__bf16)a.z; o[3] = (__bf16)a.w;
  o[4] = (__bf16)b.x; o[5] = (__bf16)b.y; o[6] = (__bf16)b.z; o[7] = (__bf16)b.w;
  *(bf16x8*)&dst[8*off] = o;
}

// ---------------------------------------------------------------------------
// NT GEMM 128x128, global_load_lds staging (unpadded LDS stride 64),
// LDS-swizzle epilogue with coalesced 16B stores.
// z = 0/1/2 -> Q / K / V; Q,K stored [B,H,S,Dh]; V stored [B,H,Dh,S]
// ---------------------------------------------------------------------------
__global__ __launch_bounds__(256) void gemm_qkv(
    const __bf16* __restrict__ xb,
    const __bf16* __restrict__ wq, const __bf16* __restrict__ wk,
    const __bf16* __restrict__ wv,
    const float* __restrict__ bq, const float* __restrict__ bk,
    const float* __restrict__ bv,
    __bf16* __restrict__ Qb, __bf16* __restrict__ Kb, __bf16* __restrict__ Vt)
{
  const int z = blockIdx.z;
  const __bf16* W    = (z == 0) ? wq : (z == 1) ? wk : wv;
  const float*  bias = (z == 0) ? bq : (z == 1) ? bk : bv;

  __shared__ __bf16 S[2][128*64];          // As, Bs; reused as C-stage (32 KB)
  __bf16* As = S[0];
  __bf16* Bs = S[1];

  const int tid  = threadIdx.x;
  const int m0   = blockIdx.x * 128, n0 = blockIdx.y * 128;
  const int w    = tid >> 6, lane = tid & 63, quad = lane >> 4, l16 = lane & 15;
  const int wm   = (w >> 1) * 64, wn = (w & 1) * 64;
  const int lrow = lane >> 3;              // 0..7
  const int lcol = (lane & 7) * 8;         // element col within 64

  f32x4 acc[4][4] = {};

  const __bf16* Ag = xb + (size_t)m0 * DIM;
  const __bf16* Bg = W  + (size_t)n0 * DIM;

  for (int k0 = 0; k0 < DIM; k0 += 64) {
#pragma unroll
    for (int i = 0; i < 4; ++i) {
      const int rb = w*32 + i*8;
      async_ld16(&Ag[(size_t)(rb + lrow)*DIM + k0 + lcol], &As[rb*64]);
      async_ld16(&Bg[(size_t)(rb + lrow)*DIM + k0 + lcol], &Bs[rb*64]);
    }
    __syncthreads();
#pragma unroll
    for (int kk = 0; kk < 2; ++kk) {
      const int ko = kk*32 + quad*8;
      bf16x8 af[4], bfr[4];
#pragma unroll
      for (int f = 0; f < 4; ++f) {
        af[f]  = *(const bf16x8*)&As[(wm + f*16 + l16)*64 + ko];
        bfr[f] = *(const bf16x8*)&Bs[(wn + f*16 + l16)*64 + ko];
      }
#pragma unroll
      for (int fm = 0; fm < 4; ++fm)
#pragma unroll
        for (int fn = 0; fn < 4; ++fn)
          acc[fm][fn] = MFMA16(af[fm], bfr[fn], acc[fm][fn]);
    }
    __syncthreads();
  }

  // ---- epilogue: acc -> swizzled LDS tile -> coalesced 16B stores ----
  __bf16* Cs = &S[0][0];                   // 128*128 bf16 = 32 KB (all of S)
  if (z < 2) {
#pragma unroll
    for (int fm = 0; fm < 4; ++fm)
#pragma unroll
      for (int fn = 0; fn < 4; ++fn) {
        const int col = wn + fn*16 + l16;
        const float bc = bias[n0 + col];
        const int chunk = col >> 3, ce = col & 7;
#pragma unroll
        for (int r = 0; r < 4; ++r) {
          const int row = wm + fm*16 + quad*4 + r;
          Cs[row*128 + ((chunk ^ (row & 7)) << 3) + ce] = (__bf16)(acc[fm][fn][r] + bc);
        }
      }
  } else {
#pragma unroll
    for (int fm = 0; fm < 4; ++fm)
#pragma unroll
      for (int fn = 0; fn < 4; ++fn) {
        const int dhcol = wn + fn*16 + l16;
        const float bc = bias[n0 + dhcol];
        const int sbase = wm + fm*16 + quad*4;
        const int schunk = sbase >> 3, so = sbase & 7;
        __bf16* p = &Cs[dhcol*128 + ((schunk ^ (dhcol & 7)) << 3) + so];
#pragma unroll
        for (int r = 0; r < 4; ++r)
          p[r] = (__bf16)(acc[fm][fn][r] + bc);
      }
  }
  __syncthreads();
  {
    const int row = tid >> 1, half = tid & 1;
    if (z < 2) {
      __bf16* O = (z == 0) ? Qb : Kb;
      const int s = m0 + row, bb = s >> 11, ss = s & 2047;
#pragma unroll
      for (int j = 0; j < 8; ++j) {
        const int chunk = half*8 + j;
        bf16x8 v = *(const bf16x8*)&Cs[row*128 + ((chunk ^ (row & 7)) << 3)];
        const int colg = n0 + chunk*8;
        const int hh = colg >> 6, dh = colg & 63;
        *(bf16x8*)&O[((size_t)(bb*NH + hh)*SEQ + ss)*DH + dh] = v;
      }
    } else {
      const int colg = n0 + row;           // dh column
      const int hh = colg >> 6, dh = colg & 63;
      const int bb = m0 >> 11, s0s = m0 & 2047;
#pragma unroll
      for (int j = 0; j < 8; ++j) {
        const int chunk = half*8 + j;
        bf16x8 v = *(const bf16x8*)&Cs[row*128 + ((chunk ^ (row & 7)) << 3)];
        *(bf16x8*)&Vt[((size_t)(bb*NH + hh)*DH + dh)*SEQ + s0s + chunk*8] = v;
      }
    }
  }
}

// ---------------------------------------------------------------------------
// Output projection with the same staging; direct f32 stores.
// ---------------------------------------------------------------------------
__global__ __launch_bounds__(256) void gemm_out(
    const __bf16* __restrict__ attnb, const __bf16* __restrict__ wo,
    const float* __restrict__ bo, float* __restrict__ out)
{
  __shared__ __bf16 S[2][128*64];
  __bf16* As = S[0];
  __bf16* Bs = S[1];

  const int tid = threadIdx.x;
  const int m0  = blockIdx.x * 128, n0 = blockIdx.y * 128;
  const int w   = tid >> 6, lane = tid & 63, quad = lane >> 4, l16 = lane & 15;
  const int wm  = (w >> 1) * 64, wn = (w & 1) * 64;
  const int lrow = lane >> 3, lcol = (lane & 7) * 8;

  f32x4 acc[4][4] = {};

  const __bf16* Ag = attnb + (size_t)m0 * DIM;
  const __bf16* Bg = wo    + (size_t)n0 * DIM;

  for (int k0 = 0; k0 < DIM; k0 += 64) {
#pragma unroll
    for (int i = 0; i < 4; ++i) {
      const int rb = w*32 + i*8;
      async_ld16(&Ag[(size_t)(rb + lrow)*DIM + k0 + lcol], &As[rb*64]);
      async_ld16(&Bg[(size_t)(rb + lrow)*DIM + k0 + lcol], &Bs[rb*64]);
    }
    __syncthreads();
#pragma unroll
    for (int kk = 0; kk < 2; ++kk) {
      const int ko = kk*32 + quad*8;
      bf16x8 af[4], bfr[4];
#pragma unroll
      for (int f = 0; f < 4; ++f) {
        af[f]  = *(const bf16x8*)&As[(wm + f*16 + l16)*64 + ko];
        bfr[f] = *(const bf16x8*)&Bs[(wn + f*16 + l16)*64 + ko];
      }
#pragma unroll
      for (int fm = 0; fm < 4; ++fm)
#pragma unroll
        for (int fn = 0; fn < 4; ++fn)
          acc[fm][fn] = MFMA16(af[fm], bfr[fn], acc[fm][fn]);
    }
    __syncthreads();
  }

#pragma unroll
  for (int fm = 0; fm < 4; ++fm) {
#pragma unroll
    for (int fn = 0; fn < 4; ++fn) {
      const int col  = n0 + wn + fn*16 + l16;
      const float bc = bo[col];
#pragma unroll
      for (int r = 0; r < 4; ++r) {
        const int row = m0 + wm + fm*16 + quad*4 + r;
        out[(size_t)row*DIM + col] = acc[fm][fn][r] + bc;
      }
    }
  }
}

// ---------------------------------------------------------------------------
// Flash v7: statically balanced pairing. One wave per block; wave owns TWO
// 16-row q-groups: A = 16-row tile j (light), B = tile 127-j (heavy).
// Work per wave = ntA+ntB ~ 33 k-tiles, CONSTANT across all 2048 waves ->
// no straggler tail, sustained occupancy. K/V tiles shared by both groups
// while both active. S^T orientation (q in lane index): per-lane softmax,
// 2 shfls per reduction. Q pre-scaled by 0.125*log2(e) -> exp2f directly.
// ---------------------------------------------------------------------------
__global__ __launch_bounds__(64) void flash_attn(
    const __bf16* __restrict__ Qb, const __bf16* __restrict__ Kb,
    const __bf16* __restrict__ Vt, __bf16* __restrict__ attnb)
{
  const int idx = blockIdx.x;
  const int bh  = idx & 31;                    // spread across XCDs
  const int j   = idx >> 5;                    // 0..63 pair index
  const int b   = bh >> 3, h = bh & 7;
  const int lane = threadIdx.x & 63, quad = lane >> 4, l16 = lane & 15;
  const int q0A = j * 16;                      // light 16-row group
  const int q0B = (127 - j) * 16;              // heavy 16-row group
  const int ntA = (q0A >> 6) + 1;              // k-tiles for A (<=16)
  const int ntB = (q0B >> 6) + 1;              // k-tiles for B (>=16)

  const __bf16* Qp = Qb + (size_t)bh * SEQ * DH;   // [s][dh]
  const __bf16* Kp = Kb + (size_t)bh * SEQ * DH;   // [s][dh]
  const __bf16* Vp = Vt + (size_t)bh * DH * SEQ;   // [dh][s]

  __shared__ __bf16 Pt[32*72];                 // rows 0-15: A, 16-31: B

  // Q B-frags, pre-scaled by 1/sqrt(Dh) * log2(e) (softmax in base 2)
  const float qs = 0.125f * 1.44269504088896f;
  bf16x8 qfA[2], qfB[2];
#pragma unroll
  for (int kc = 0; kc < 2; ++kc) {
    bf16x8 qa = *(const bf16x8*)&Qp[(size_t)(q0A + l16)*DH + kc*32 + quad*8];
    bf16x8 qb = *(const bf16x8*)&Qp[(size_t)(q0B + l16)*DH + kc*32 + quad*8];
#pragma unroll
    for (int e = 0; e < 8; ++e) {
      qa[e] = (__bf16)((float)qa[e] * qs);
      qb[e] = (__bf16)((float)qb[e] * qs);
    }
    qfA[kc] = qa; qfB[kc] = qb;
  }

  f32x4 oA[4] = {}, oB[4] = {};                // O^T accum [dhf]
  float mA = -1e30f, lA = 0.f, mB = -1e30f, lB = 0.f;

  bf16x8 kf[4][2];                             // K-frags [mf(key)][kc(d)]
  bf16x8 vf[4][2];                             // V-frags [dhf][kc(key)]
#pragma unroll
  for (int mf = 0; mf < 4; ++mf)
#pragma unroll
    for (int kc = 0; kc < 2; ++kc)
      kf[mf][kc] = *(const bf16x8*)&Kp[(size_t)(mf*16 + l16)*DH + kc*32 + quad*8];
#pragma unroll
  for (int df = 0; df < 4; ++df)
#pragma unroll
    for (int kc = 0; kc < 2; ++kc)
      vf[df][kc] = *(const bf16x8*)&Vp[(size_t)(df*16 + l16)*SEQ + kc*32 + quad*8];

  // per-lane online softmax for one 16-row group (q = base + l16)
  auto softmax_update = [&](f32x4 (&s)[4], float& m_, float& l_, f32x4 (&o)[4]) {
    float mx = fmaxf(fmaxf(fmaxf(s[0][0], s[0][1]), fmaxf(s[0][2], s[0][3])),
                     fmaxf(fmaxf(s[1][0], s[1][1]), fmaxf(s[1][2], s[1][3])));
    float mx2 = fmaxf(fmaxf(fmaxf(s[2][0], s[2][1]), fmaxf(s[2][2], s[2][3])),
                      fmaxf(fmaxf(s[3][0], s[3][1]), fmaxf(s[3][2], s[3][3])));
    mx = fmaxf(mx, mx2);
    mx = fmaxf(mx, __shfl_xor(mx, 16));
    mx = fmaxf(mx, __shfl_xor(mx, 32));
    const float mn = fmaxf(m_, mx);
    const float al = exp2f(m_ - mn);
    m_ = mn;
    float sum = 0.f;
#pragma unroll
    for (int mf = 0; mf < 4; ++mf)
#pragma unroll
      for (int r = 0; r < 4; ++r) {
        const float e = exp2f(s[mf][r] - mn);
        s[mf][r] = e;
        sum += e;
      }
    sum += __shfl_xor(sum, 16);
    sum += __shfl_xor(sum, 32);
    l_ = l_ * al + sum;
#pragma unroll
    for (int df = 0; df < 4; ++df)
#pragma unroll
      for (int r = 0; r < 4; ++r)
        o[df][r] *= al;
  };

  for (int kt = 0; kt < ntB; ++kt) {
    const int k0 = kt * 64;
    const int kn0 = (kt + 1 < ntB) ? k0 + 64 : k0;
    const bool doA = (kt < ntA);

    // ---- S^T = K Q^T : C[key][q] ----
    f32x4 sA[4], sB[4];
#pragma unroll
    for (int mf = 0; mf < 4; ++mf) { sB[mf] = f32x4{}; }
#pragma unroll
    for (int mf = 0; mf < 4; ++mf) {
      sB[mf] = MFMA16(kf[mf][0], qfB[0], sB[mf]);
      sB[mf] = MFMA16(kf[mf][1], qfB[1], sB[mf]);
    }
    if (doA) {
#pragma unroll
      for (int mf = 0; mf < 4; ++mf) { sA[mf] = f32x4{}; }
#pragma unroll
      for (int mf = 0; mf < 4; ++mf) {
        sA[mf] = MFMA16(kf[mf][0], qfA[0], sA[mf]);
        sA[mf] = MFMA16(kf[mf][1], qfA[1], sA[mf]);
      }
    }

    // ---- early-issue K(t+1) ----
#pragma unroll
    for (int mf = 0; mf < 4; ++mf)
#pragma unroll
      for (int kc = 0; kc < 2; ++kc)
        kf[mf][kc] = *(const bf16x8*)&Kp[(size_t)(kn0 + mf*16 + l16)*DH + kc*32 + quad*8];

    // ---- causal masks (last tile(s) of each group only) ----
    if (doA && (k0 + 63 > q0A)) {
      const int q = q0A + l16;
#pragma unroll
      for (int mf = 0; mf < 4; ++mf) {
        const int kb = k0 + mf*16 + quad*4;
#pragma unroll
        for (int r = 0; r < 4; ++r)
          if (kb + r > q) sA[mf][r] = -1e30f;
      }
    }
    if (k0 + 63 > q0B) {
      const int q = q0B + l16;
#pragma unroll
      for (int mf = 0; mf < 4; ++mf) {
        const int kb = k0 + mf*16 + quad*4;
#pragma unroll
        for (int r = 0; r < 4; ++r)
          if (kb + r > q) sB[mf][r] = -1e30f;
      }
    }

    // ---- softmax ----
    if (doA) softmax_update(sA, mA, lA, oA);
    softmax_update(sB, mB, lB, oB);

    // ---- P^T -> LDS (b64 writes), read back as B-frags ----
    if (doA) {
#pragma unroll
      for (int mf = 0; mf < 4; ++mf) {
        bf16x4 p4;
#pragma unroll
        for (int r = 0; r < 4; ++r) p4[r] = (__bf16)sA[mf][r];
        *(bf16x4*)&Pt[l16*72 + mf*16 + quad*4] = p4;
      }
    }
#pragma unroll
    for (int mf = 0; mf < 4; ++mf) {
      bf16x4 p4;
#pragma unroll
      for (int r = 0; r < 4; ++r) p4[r] = (__bf16)sB[mf][r];
      *(bf16x4*)&Pt[(16 + l16)*72 + mf*16 + quad*4] = p4;
    }
    bf16x8 pbA[2], pbB[2];
    if (doA) {
#pragma unroll
      for (int kc = 0; kc < 2; ++kc)
        pbA[kc] = *(const bf16x8*)&Pt[l16*72 + kc*32 + quad*8];
    }
#pragma unroll
    for (int kc = 0; kc < 2; ++kc)
      pbB[kc] = *(const bf16x8*)&Pt[(16 + l16)*72 + kc*32 + quad*8];

    // ---- O^T += V^T P^T ----
#pragma unroll
    for (int df = 0; df < 4; ++df) {
      oB[df] = MFMA16(vf[df][0], pbB[0], oB[df]);
      oB[df] = MFMA16(vf[df][1], pbB[1], oB[df]);
    }
    if (doA) {
#pragma unroll
      for (int df = 0; df < 4; ++df) {
        oA[df] = MFMA16(vf[df][0], pbA[0], oA[df]);
        oA[df] = MFMA16(vf[df][1], pbA[1], oA[df]);
      }
    }

    // ---- early-issue V(t+1) ----
#pragma unroll
    for (int df = 0; df < 4; ++df)
#pragma unroll
      for (int kc = 0; kc < 2; ++kc)
        vf[df][kc] = *(const bf16x8*)&Vp[(size_t)(df*16 + l16)*SEQ + kn0 + kc*32 + quad*8];
  }

  // ---- normalize + store both groups ----
  auto store_group = [&](f32x4 (&o)[4], float l_, int q0) {
    const float inv = 1.0f / l_;
    const int q = q0 + l16;
#pragma unroll
    for (int df = 0; df < 4; ++df) {
      bf16x4 o4;
#pragma unroll
      for (int r = 0; r < 4; ++r) o4[r] = (__bf16)(o[df][r] * inv);
      *(bf16x4*)&attnb[((size_t)b*SEQ + q)*DIM + h*DH + df*16 + quad*4] = o4;
    }
  };
  store_group(oA, lA, q0A);
  store_group(oB, lB, q0B);
}

// ---------------------------------------------------------------------------
extern "C" void kernel_launch(void* const* d_in, const int* in_sizes, int n_in,
                              void* d_out, int out_size, void* d_ws, size_t ws_size,
                              hipStream_t stream) {
  const float* x  = (const float*)d_in[0];
  // d_in[1] = causal mask, unused (causality computed analytically)
  const float* Wq = (const float*)d_in[2];
  const float* bq = (const float*)d_in[3];
  const float* Wk = (const float*)d_in[4];
  const float* bk = (const float*)d_in[5];
  const float* Wv = (const float*)d_in[6];
  const float* bv = (const float*)d_in[7];
  const float* Wo = (const float*)d_in[8];
  const float* bo = (const float*)d_in[9];
  float* out = (float*)d_out;

  // workspace carve-up (bf16 elements)
  __bf16* xb    = (__bf16*)d_ws;
  __bf16* wq    = xb + (size_t)NTOK*DIM;
  __bf16* wk    = wq + DIM*DIM;
  __bf16* wv    = wk + DIM*DIM;
  __bf16* wo    = wv + DIM*DIM;
  __bf16* Qb    = wo + DIM*DIM;
  __bf16* Kb    = Qb + (size_t)NTOK*DIM;
  __bf16* Vt    = Kb + (size_t)NTOK*DIM;
  __bf16* attnb = Vt + (size_t)NTOK*DIM;

  cvt_all<<<(NTOK*DIM/8 + 4*DIM*DIM/8)/256, 256, 0, stream>>>(
      x, Wq, Wk, Wv, Wo, xb, wq, wk, wv, wo);

  gemm_qkv<<<dim3(NTOK/128, DIM/128, 3), 256, 0, stream>>>(
      xb, wq, wk, wv, bq, bk, bv, Qb, Kb, Vt);

  flash_attn<<<2048, 64, 0, stream>>>(Qb, Kb, Vt, attnb);

  gemm_out<<<dim3(NTOK/128, DIM/128), 256, 0, stream>>>(attnb, wo, bo, out);
}